// Round 1
// baseline (74.077 us; speedup 1.0000x reference)
//
#include <hip/hip_runtime.h>
#include <math.h>
#include <stdint.h>

#define NLEV 8
#define TSIZE 131072
#define TMASK (TSIZE - 1)

__global__ __launch_bounds__(256) void rif_kernel(
    const float* __restrict__ positions,
    const float* __restrict__ c2ws,
    const float* __restrict__ aabb,
    const float* __restrict__ table,
    const float* __restrict__ w1, const float* __restrict__ b1,
    const float* __restrict__ w2, const float* __restrict__ b2,
    const float* __restrict__ hw1, const float* __restrict__ hb1,
    const float* __restrict__ hw2, const float* __restrict__ hb2,
    float* __restrict__ out, int total, int S)
{
    __shared__ float sw1[512];
    __shared__ float sb1[32];
    __shared__ float sw2[512];
    __shared__ float sb2[16];
    __shared__ float shw1[1024];
    __shared__ float shb1[64];
    __shared__ float shw2[64];
    __shared__ float shb2[1];

    for (int i = threadIdx.x; i < 512; i += 256) { sw1[i] = w1[i]; sw2[i] = w2[i]; }
    for (int i = threadIdx.x; i < 1024; i += 256) shw1[i] = hw1[i];
    if (threadIdx.x < 64) { shb1[threadIdx.x] = hb1[threadIdx.x]; shw2[threadIdx.x] = hw2[threadIdx.x]; }
    if (threadIdx.x < 32) sb1[threadIdx.x] = b1[threadIdx.x];
    if (threadIdx.x < 16) sb2[threadIdx.x] = b2[threadIdx.x];
    if (threadIdx.x == 0) shb2[0] = hb2[0];
    __syncthreads();

    int gid = blockIdx.x * blockDim.x + threadIdx.x;
    if (gid >= total) return;
    int r = gid / S;

    const float* p = positions + (size_t)gid * 3;
    const float* c = c2ws + (size_t)r * 12;
    float px = p[0], py = p[1], pz = p[2];
    float c00 = c[0], c01 = c[1], c02 = c[2],  t0 = c[3];
    float c10 = c[4], c11 = c[5], c12 = c[6],  t1 = c[7];
    float c20 = c[8], c21 = c[9], c22 = c[10], t2 = c[11];

    // pos_i = (rot^T p)_i + t_w2c_i,  t_w2c = -(rot^T trans)
    // rot^T[i][j] = rot[j][i] = c[j*4+i]
    float m0 = __fadd_rn(__fadd_rn(__fmul_rn(c00, px), __fmul_rn(c10, py)), __fmul_rn(c20, pz));
    float m1 = __fadd_rn(__fadd_rn(__fmul_rn(c01, px), __fmul_rn(c11, py)), __fmul_rn(c21, pz));
    float m2 = __fadd_rn(__fadd_rn(__fmul_rn(c02, px), __fmul_rn(c12, py)), __fmul_rn(c22, pz));
    float n0 = __fadd_rn(__fadd_rn(__fmul_rn(c00, t0), __fmul_rn(c10, t1)), __fmul_rn(c20, t2));
    float n1 = __fadd_rn(__fadd_rn(__fmul_rn(c01, t0), __fmul_rn(c11, t1)), __fmul_rn(c21, t2));
    float n2 = __fadd_rn(__fadd_rn(__fmul_rn(c02, t0), __fmul_rn(c12, t1)), __fmul_rn(c22, t2));
    float posx = __fsub_rn(m0, n0);
    float posy = __fsub_rn(m1, n1);
    float posz = __fsub_rn(m2, n2);

    float a0x = aabb[0], a0y = aabb[1], a0z = aabb[2];
    float a1x = aabb[3], a1y = aabb[4], a1z = aabb[5];
    posx = __fdiv_rn(__fsub_rn(posx, a0x), __fsub_rn(a1x, a0x));
    posy = __fdiv_rn(__fsub_rn(posy, a0y), __fsub_rn(a1y, a0y));
    posz = __fdiv_rn(__fsub_rn(posz, a0z), __fsub_rn(a1z, a0z));

    bool sel = (posx > 0.f) & (posx < 1.f) & (posy > 0.f) & (posy < 1.f) & (posz > 0.f) & (posz < 1.f);
    if (!sel) { out[gid] = 0.f; return; }

    const float kScale[8] = {16.f, 28.f, 52.f, 95.f, 172.f, 312.f, 565.f, 1024.f};
    float enc[16];
    #pragma unroll
    for (int l = 0; l < NLEV; ++l) {
        float sc = kScale[l];
        float sx = posx * sc, sy = posy * sc, sz = posz * sc;
        float fx = floorf(sx), fy = floorf(sy), fz = floorf(sz);
        float wx = sx - fx, wy = sy - fy, wz = sz - fz;
        uint32_t ix = (uint32_t)(int)fx, iy = (uint32_t)(int)fy, iz = (uint32_t)(int)fz;
        uint32_t hy0 = iy * 2654435761u, hy1 = hy0 + 2654435761u;
        uint32_t hz0 = iz * 805459861u,  hz1 = hz0 + 805459861u;
        const float2* tab = (const float2*)table + (size_t)l * TSIZE;
        float f0 = 0.f, f1 = 0.f;
        #pragma unroll
        for (int cc = 0; cc < 8; ++cc) {
            uint32_t cx = (cc >> 2) & 1, cy = (cc >> 1) & 1, cz = cc & 1;
            uint32_t hh = ((ix + cx) ^ (cy ? hy1 : hy0) ^ (cz ? hz1 : hz0)) & TMASK;
            float wgt = (cx ? wx : 1.f - wx) * (cy ? wy : 1.f - wy) * (cz ? wz : 1.f - wz);
            float2 ft = tab[hh];
            f0 = fmaf(ft.x, wgt, f0);
            f1 = fmaf(ft.y, wgt, f1);
        }
        enc[2 * l] = f0;
        enc[2 * l + 1] = f1;
    }

    // MLP 1: 16 -> 32 (relu) -> 16
    float h1[32];
    #pragma unroll
    for (int j = 0; j < 32; ++j) h1[j] = sb1[j];
    #pragma unroll
    for (int i = 0; i < 16; ++i) {
        float e = enc[i];
        #pragma unroll
        for (int j = 0; j < 32; ++j) h1[j] = fmaf(e, sw1[i * 32 + j], h1[j]);
    }
    #pragma unroll
    for (int j = 0; j < 32; ++j) h1[j] = fmaxf(h1[j], 0.f);

    float h2[16];
    #pragma unroll
    for (int j = 0; j < 16; ++j) h2[j] = sb2[j];
    #pragma unroll
    for (int i = 0; i < 32; ++i) {
        float e = h1[i];
        #pragma unroll
        for (int j = 0; j < 16; ++j) h2[j] = fmaf(e, sw2[i * 16 + j], h2[j]);
    }

    // MLP 2: 16 -> 64 (relu) -> 1, streamed
    float o = shb2[0];
    #pragma unroll
    for (int j = 0; j < 64; ++j) {
        float acc = shb1[j];
        #pragma unroll
        for (int i = 0; i < 16; ++i) acc = fmaf(h2[i], shw1[i * 64 + j], acc);
        o = fmaf(fmaxf(acc, 0.f), shw2[j], o);
    }

    float x = o - 5.0f;
    out[gid] = 1.0f / (1.0f + expf(-x));
}

extern "C" void kernel_launch(void* const* d_in, const int* in_sizes, int n_in,
                              void* d_out, int out_size, void* d_ws, size_t ws_size,
                              hipStream_t stream) {
    const float* positions = (const float*)d_in[0];
    const float* c2ws      = (const float*)d_in[1];
    const float* aabb      = (const float*)d_in[2];
    const float* table     = (const float*)d_in[3];
    const float* w1  = (const float*)d_in[4];
    const float* b1  = (const float*)d_in[5];
    const float* w2  = (const float*)d_in[6];
    const float* b2  = (const float*)d_in[7];
    const float* hw1 = (const float*)d_in[8];
    const float* hb1 = (const float*)d_in[9];
    const float* hw2 = (const float*)d_in[10];
    const float* hb2 = (const float*)d_in[11];

    int R = in_sizes[1] / 12;
    int total = in_sizes[0] / 3;
    int S = total / R;

    int threads = 256;
    int blocks = (total + threads - 1) / threads;
    hipLaunchKernelGGL(rif_kernel, dim3(blocks), dim3(threads), 0, stream,
                       positions, c2ws, aabb, table,
                       w1, b1, w2, b2, hw1, hb1, hw2, hb2,
                       (float*)d_out, total, S);
}

// Round 2
// 69.091 us; speedup vs baseline: 1.0722x; 1.0722x over previous
//
#include <hip/hip_runtime.h>
#include <math.h>
#include <stdint.h>

#define NLEV 8
#define TSIZE 131072
#define TMASK (TSIZE - 1)

__global__ __launch_bounds__(256, 4) void rif_kernel(
    const float* __restrict__ positions,
    const float* __restrict__ c2ws,
    const float* __restrict__ aabb,
    const float* __restrict__ table,
    const float* __restrict__ w1, const float* __restrict__ b1,
    const float* __restrict__ w2, const float* __restrict__ b2,
    const float* __restrict__ hw1, const float* __restrict__ hb1,
    const float* __restrict__ hw2, const float* __restrict__ hb2,
    float* __restrict__ out, int total, int S)
{
    __shared__ float sw1[512];
    __shared__ float sb1[32];
    __shared__ float sw2[512];
    __shared__ float sb2[16];
    __shared__ float shw1[1024];
    __shared__ float shb1[64];
    __shared__ float shw2[64];
    __shared__ float shb2[1];

    for (int i = threadIdx.x; i < 512; i += 256) { sw1[i] = w1[i]; sw2[i] = w2[i]; }
    for (int i = threadIdx.x; i < 1024; i += 256) shw1[i] = hw1[i];
    if (threadIdx.x < 64) { shb1[threadIdx.x] = hb1[threadIdx.x]; shw2[threadIdx.x] = hw2[threadIdx.x]; }
    if (threadIdx.x < 32) sb1[threadIdx.x] = b1[threadIdx.x];
    if (threadIdx.x < 16) sb2[threadIdx.x] = b2[threadIdx.x];
    if (threadIdx.x == 0) shb2[0] = hb2[0];
    __syncthreads();

    int gid = blockIdx.x * blockDim.x + threadIdx.x;
    if (gid >= total) return;
    int r = gid / S;

    const float* p = positions + (size_t)gid * 3;
    const float* c = c2ws + (size_t)r * 12;
    float px = p[0], py = p[1], pz = p[2];
    float c00 = c[0], c01 = c[1], c02 = c[2],  t0 = c[3];
    float c10 = c[4], c11 = c[5], c12 = c[6],  t1 = c[7];
    float c20 = c[8], c21 = c[9], c22 = c[10], t2 = c[11];

    // pos_i = (rot^T p)_i - (rot^T trans)_i, in reference op order (no FMA contraction)
    float m0 = __fadd_rn(__fadd_rn(__fmul_rn(c00, px), __fmul_rn(c10, py)), __fmul_rn(c20, pz));
    float m1 = __fadd_rn(__fadd_rn(__fmul_rn(c01, px), __fmul_rn(c11, py)), __fmul_rn(c21, pz));
    float m2 = __fadd_rn(__fadd_rn(__fmul_rn(c02, px), __fmul_rn(c12, py)), __fmul_rn(c22, pz));
    float n0 = __fadd_rn(__fadd_rn(__fmul_rn(c00, t0), __fmul_rn(c10, t1)), __fmul_rn(c20, t2));
    float n1 = __fadd_rn(__fadd_rn(__fmul_rn(c01, t0), __fmul_rn(c11, t1)), __fmul_rn(c21, t2));
    float n2 = __fadd_rn(__fadd_rn(__fmul_rn(c02, t0), __fmul_rn(c12, t1)), __fmul_rn(c22, t2));
    float posx = __fsub_rn(m0, n0);
    float posy = __fsub_rn(m1, n1);
    float posz = __fsub_rn(m2, n2);

    float a0x = aabb[0], a0y = aabb[1], a0z = aabb[2];
    float a1x = aabb[3], a1y = aabb[4], a1z = aabb[5];
    posx = __fdiv_rn(__fsub_rn(posx, a0x), __fsub_rn(a1x, a0x));
    posy = __fdiv_rn(__fsub_rn(posy, a0y), __fsub_rn(a1y, a0y));
    posz = __fdiv_rn(__fsub_rn(posz, a0z), __fsub_rn(a1z, a0z));

    bool sel = (posx > 0.f) & (posx < 1.f) & (posy > 0.f) & (posy < 1.f) & (posz > 0.f) & (posz < 1.f);
    if (!sel) { out[gid] = 0.f; return; }

    const float kScale[8] = {16.f, 28.f, 52.f, 95.f, 172.f, 312.f, 565.f, 1024.f};

    // ---- Phase 1: all addresses + issue all 64 gathers into live registers ----
    float wxs[8], wys[8], wzs[8];
    float2 ft[8][8];
    #pragma unroll
    for (int l = 0; l < NLEV; ++l) {
        float sc = kScale[l];
        float sx = posx * sc, sy = posy * sc, sz = posz * sc;
        float fx = floorf(sx), fy = floorf(sy), fz = floorf(sz);
        wxs[l] = sx - fx; wys[l] = sy - fy; wzs[l] = sz - fz;
        uint32_t ix = (uint32_t)(int)fx, iy = (uint32_t)(int)fy, iz = (uint32_t)(int)fz;
        uint32_t hy0 = iy * 2654435761u, hy1 = hy0 + 2654435761u;
        uint32_t hz0 = iz * 805459861u,  hz1 = hz0 + 805459861u;
        const float2* tab = (const float2*)table + (size_t)l * TSIZE;
        #pragma unroll
        for (int cc = 0; cc < 8; ++cc) {
            uint32_t cx = (cc >> 2) & 1, cy = (cc >> 1) & 1, cz = cc & 1;
            uint32_t hh = ((ix + cx) ^ (cy ? hy1 : hy0) ^ (cz ? hz1 : hz0)) & TMASK;
            ft[l][cc] = tab[hh];
        }
    }

    // ---- Phase 2: trilinear accumulate ----
    float enc[16];
    #pragma unroll
    for (int l = 0; l < NLEV; ++l) {
        float wx = wxs[l], wy = wys[l], wz = wzs[l];
        float ux = 1.f - wx, uy = 1.f - wy, uz = 1.f - wz;
        float q00 = uy * uz, q01 = uy * wz, q10 = wy * uz, q11 = wy * wz;
        float f0, f1;
        f0 = ft[l][0].x * (ux * q00); f1 = ft[l][0].y * (ux * q00);
        f0 = fmaf(ft[l][1].x, ux * q01, f0); f1 = fmaf(ft[l][1].y, ux * q01, f1);
        f0 = fmaf(ft[l][2].x, ux * q10, f0); f1 = fmaf(ft[l][2].y, ux * q10, f1);
        f0 = fmaf(ft[l][3].x, ux * q11, f0); f1 = fmaf(ft[l][3].y, ux * q11, f1);
        f0 = fmaf(ft[l][4].x, wx * q00, f0); f1 = fmaf(ft[l][4].y, wx * q00, f1);
        f0 = fmaf(ft[l][5].x, wx * q01, f0); f1 = fmaf(ft[l][5].y, wx * q01, f1);
        f0 = fmaf(ft[l][6].x, wx * q10, f0); f1 = fmaf(ft[l][6].y, wx * q10, f1);
        f0 = fmaf(ft[l][7].x, wx * q11, f0); f1 = fmaf(ft[l][7].y, wx * q11, f1);
        enc[2 * l] = f0;
        enc[2 * l + 1] = f1;
    }

    // MLP 1: 16 -> 32 (relu) -> 16
    float h1[32];
    #pragma unroll
    for (int j = 0; j < 32; ++j) h1[j] = sb1[j];
    #pragma unroll
    for (int i = 0; i < 16; ++i) {
        float e = enc[i];
        #pragma unroll
        for (int j = 0; j < 32; ++j) h1[j] = fmaf(e, sw1[i * 32 + j], h1[j]);
    }
    #pragma unroll
    for (int j = 0; j < 32; ++j) h1[j] = fmaxf(h1[j], 0.f);

    float h2[16];
    #pragma unroll
    for (int j = 0; j < 16; ++j) h2[j] = sb2[j];
    #pragma unroll
    for (int i = 0; i < 32; ++i) {
        float e = h1[i];
        #pragma unroll
        for (int j = 0; j < 16; ++j) h2[j] = fmaf(e, sw2[i * 16 + j], h2[j]);
    }

    // MLP 2: 16 -> 64 (relu) -> 1, streamed
    float o = shb2[0];
    #pragma unroll
    for (int j = 0; j < 64; ++j) {
        float acc = shb1[j];
        #pragma unroll
        for (int i = 0; i < 16; ++i) acc = fmaf(h2[i], shw1[i * 64 + j], acc);
        o = fmaf(fmaxf(acc, 0.f), shw2[j], o);
    }

    float x = o - 5.0f;
    out[gid] = 1.0f / (1.0f + expf(-x));
}

extern "C" void kernel_launch(void* const* d_in, const int* in_sizes, int n_in,
                              void* d_out, int out_size, void* d_ws, size_t ws_size,
                              hipStream_t stream) {
    const float* positions = (const float*)d_in[0];
    const float* c2ws      = (const float*)d_in[1];
    const float* aabb      = (const float*)d_in[2];
    const float* table     = (const float*)d_in[3];
    const float* w1  = (const float*)d_in[4];
    const float* b1  = (const float*)d_in[5];
    const float* w2  = (const float*)d_in[6];
    const float* b2  = (const float*)d_in[7];
    const float* hw1 = (const float*)d_in[8];
    const float* hb1 = (const float*)d_in[9];
    const float* hw2 = (const float*)d_in[10];
    const float* hb2 = (const float*)d_in[11];

    int R = in_sizes[1] / 12;
    int total = in_sizes[0] / 3;
    int S = total / R;

    int threads = 256;
    int blocks = (total + threads - 1) / threads;
    hipLaunchKernelGGL(rif_kernel, dim3(blocks), dim3(threads), 0, stream,
                       positions, c2ws, aabb, table,
                       w1, b1, w2, b2, hw1, hb1, hw2, hb2,
                       (float*)d_out, total, S);
}